// Round 1
// baseline (797.586 us; speedup 1.0000x reference)
//
#include <hip/hip_runtime.h>

#define H 512
#define OW 128
#define NB 16384
#define BM 128
#define BK 64
#define LDA 72      // sA row stride (bf16 elems), padded for bank spread
#define LDB 72      // sBt row stride
#define LDH 136     // sH / sW2 row stride

typedef float f32x4 __attribute__((ext_vector_type(4)));
typedef short short8 __attribute__((ext_vector_type(8)));
typedef unsigned short ushort4v __attribute__((ext_vector_type(4)));
typedef unsigned short ushort8v __attribute__((ext_vector_type(8)));

static __device__ __forceinline__ unsigned short f2bf(float f) {
    union { float f; unsigned u; } v; v.f = f;
    return (unsigned short)((v.u + 0x7FFFu + ((v.u >> 16) & 1u)) >> 16);  // RNE
}

static __device__ __forceinline__ f32x4 mfma16(short8 a, short8 b, f32x4 c) {
    return __builtin_amdgcn_mfma_f32_16x16x32_bf16(a, b, c, 0, 0, 0);
}

// ---- prep: transpose + bf16-cast weights into ws ----
// W1: 15 instances of [K=512][N=512] fp32 -> [N=512][K=512] bf16
__global__ void prep_w1(const float* __restrict__ share_W1,
                        const float* __restrict__ task_W1,
                        unsigned short* __restrict__ w1t) {
    const int inst = blockIdx.z;
    const float* src = (inst < 5) ? (share_W1 + (size_t)inst * H * H)
                                  : (task_W1 + (size_t)(inst - 5) * H * H);
    unsigned short* dst = w1t + (size_t)inst * H * H;
    const int g = blockIdx.x * 256 + threadIdx.x;   // 0..32767
    const int n = g & (H - 1);
    const int kc = g >> 9;                          // 0..63
    float v[8];
#pragma unroll
    for (int i = 0; i < 8; ++i) v[i] = src[(size_t)(kc * 8 + i) * H + n];
    ushort8v o;
#pragma unroll
    for (int i = 0; i < 8; ++i) o[i] = f2bf(v[i]);
    *(ushort8v*)&dst[(size_t)n * H + kc * 8] = o;
}

// W2: 15 instances of [K=512][N=128] fp32 -> [N=128][K=512] bf16
__global__ void prep_w2(const float* __restrict__ share_W2,
                        const float* __restrict__ task_W2,
                        unsigned short* __restrict__ w2t) {
    const int inst = blockIdx.z;
    const float* src = (inst < 5) ? (share_W2 + (size_t)inst * H * OW)
                                  : (task_W2 + (size_t)(inst - 5) * H * OW);
    unsigned short* dst = w2t + (size_t)inst * OW * H;
    const int g = blockIdx.x * 256 + threadIdx.x;   // 0..8191
    const int n = g & (OW - 1);
    const int kc = g >> 7;                          // 0..63
    float v[8];
#pragma unroll
    for (int i = 0; i < 8; ++i) v[i] = src[(size_t)(kc * 8 + i) * OW + n];
    ushort8v o;
#pragma unroll
    for (int i = 0; i < 8; ++i) o[i] = f2bf(v[i]);
    *(ushort8v*)&dst[(size_t)n * H + kc * 8] = o;
}

// ---- fused expert kernel ----
// block: 256 thr (4 waves 2x2, wave tile 64x64 of the 128x128 output)
// per block: rows rowtile*128..+128 of one (bank z, expert e)
__global__ __launch_bounds__(256, 2) void expert_fused(
    const float* __restrict__ share_x, const float* __restrict__ task_x0,
    const float* __restrict__ task_x1,
    const float* __restrict__ share_b1, const float* __restrict__ task_b1,
    const float* __restrict__ share_b2, const float* __restrict__ task_b2,
    const unsigned short* __restrict__ w1t, const unsigned short* __restrict__ w2t,
    float* __restrict__ out)
{
    // region A (sA+sBt) aliases sW2 (GEMM2 staging); sH separate
    __shared__ unsigned short smem[18432 + 17408];   // 71,680 B
    unsigned short* sA  = smem;                // [128][LDA]  x tile (bf16)
    unsigned short* sBt = smem + BM * LDA;     // [128][LDB]  W1t tile
    unsigned short* sW2 = smem;                // [128][LDH]  W2t chunk (alias)
    unsigned short* sH  = smem + 18432;        // [128][LDH]  h chunk (bf16)

    const int tid  = threadIdx.x;
    const int lane = tid & 63;
    const int wave = tid >> 6;
    const int wy = wave >> 1, wx = wave & 1;
    const int lm = lane & 15;
    const int lq = lane >> 4;

    const int rowtile = blockIdx.x;   // 0..127
    const int e = blockIdx.y;         // 0..4
    const int z = blockIdx.z;         // 0..2
    const int inst = z * 5 + e;

    const float* x  = (z == 0) ? share_x : (z == 1 ? task_x0 : task_x1);
    const float* b1 = (z == 0) ? (share_b1 + e * H)  : (task_b1 + ((z - 1) * 5 + e) * H);
    const float* b2 = (z == 0) ? (share_b2 + e * OW) : (task_b2 + ((z - 1) * 5 + e) * OW);
    const unsigned short* W1 = w1t + (size_t)inst * H * H;    // [n=512][k=512]
    const unsigned short* W2 = w2t + (size_t)inst * OW * H;   // [n=128][k=512]
    const float* xrow = x + (size_t)rowtile * BM * H;
    float* op = out + (size_t)inst * NB * OW + (size_t)rowtile * BM * OW;

    const f32x4 z4 = {0.f, 0.f, 0.f, 0.f};
    f32x4 acc_o[4][4];
#pragma unroll
    for (int i = 0; i < 4; ++i)
#pragma unroll
        for (int j = 0; j < 4; ++j) acc_o[i][j] = z4;

    for (int no = 0; no < 4; ++no) {            // h-column chunk = no*128
        f32x4 acc_h[4][4];
#pragma unroll
        for (int i = 0; i < 4; ++i)
#pragma unroll
            for (int j = 0; j < 4; ++j) acc_h[i][j] = z4;

        for (int kt = 0; kt < 8; ++kt) {        // K tiles of 64
            const int k0 = kt * BK;
            {   // stage sA: x rows 128 x 64k (fp32 -> bf16)
                const int r0 = tid >> 4;        // 0..15
                const int c4 = tid & 15;        // float4 column
#pragma unroll
                for (int it = 0; it < 8; ++it) {
                    const int r = r0 + it * 16;
                    const float4 v = *(const float4*)&xrow[(size_t)r * H + k0 + c4 * 4];
                    ushort4v w;
                    w[0] = f2bf(v.x); w[1] = f2bf(v.y); w[2] = f2bf(v.z); w[3] = f2bf(v.w);
                    *(ushort4v*)&sA[r * LDA + c4 * 4] = w;
                }
            }
            {   // stage sBt: W1t rows (no*128..+128) x k slice 64 (already bf16, k-contig)
                const int n0 = tid >> 3;        // 0..31
                const int ch = tid & 7;         // 16B chunk in k
#pragma unroll
                for (int it = 0; it < 4; ++it) {
                    const int n = n0 + it * 32;
                    ushort8v v = *(const ushort8v*)&W1[(size_t)(no * 128 + n) * H + k0 + ch * 8];
                    *(ushort8v*)&sBt[n * LDB + ch * 8] = v;
                }
            }
            __syncthreads();
#pragma unroll
            for (int kk = 0; kk < 2; ++kk) {
                short8 af[4], bfr[4];
#pragma unroll
                for (int i = 0; i < 4; ++i)
                    af[i] = *(short8*)&sA[(wy * 64 + i * 16 + lm) * LDA + kk * 32 + lq * 8];
#pragma unroll
                for (int j = 0; j < 4; ++j)
                    bfr[j] = *(short8*)&sBt[(wx * 64 + j * 16 + lm) * LDB + kk * 32 + lq * 8];
#pragma unroll
                for (int i = 0; i < 4; ++i)
#pragma unroll
                    for (int j = 0; j < 4; ++j)
                        acc_h[i][j] = mfma16(af[i], bfr[j], acc_h[i][j]);
            }
            __syncthreads();
        }

        // h epilogue: + b1, relu, bf16 -> sH  (C/D layout: row = lq*4+r, col = lm)
#pragma unroll
        for (int j = 0; j < 4; ++j) {
            const int col = wx * 64 + j * 16 + lm;
            const float b1v = b1[no * 128 + col];
#pragma unroll
            for (int i = 0; i < 4; ++i)
#pragma unroll
                for (int r = 0; r < 4; ++r) {
                    const int row = wy * 64 + i * 16 + lq * 4 + r;
                    float v = acc_h[i][j][r] + b1v;
                    v = fmaxf(v, 0.f);
                    sH[row * LDH + col] = f2bf(v);
                }
        }
        {   // stage sW2: W2t[n=0..127][k = no*128..+128]  (overwrites sA/sBt region)
            const int n0 = tid >> 4;            // 0..15
            const int ch = tid & 15;
#pragma unroll
            for (int it = 0; it < 8; ++it) {
                const int n = n0 + it * 16;
                ushort8v v = *(const ushort8v*)&W2[(size_t)n * H + no * 128 + ch * 8];
                *(ushort8v*)&sW2[n * LDH + ch * 8] = v;
            }
        }
        __syncthreads();
        // GEMM2 accumulate: acc_o += h_chunk @ W2_chunk   (K = 128)
#pragma unroll
        for (int kk = 0; kk < 4; ++kk) {
            short8 af[4], bfr[4];
#pragma unroll
            for (int i = 0; i < 4; ++i)
                af[i] = *(short8*)&sH[(wy * 64 + i * 16 + lm) * LDH + kk * 32 + lq * 8];
#pragma unroll
            for (int j = 0; j < 4; ++j)
                bfr[j] = *(short8*)&sW2[(wx * 64 + j * 16 + lm) * LDH + kk * 32 + lq * 8];
#pragma unroll
            for (int i = 0; i < 4; ++i)
#pragma unroll
                for (int j = 0; j < 4; ++j)
                    acc_o[i][j] = mfma16(af[i], bfr[j], acc_o[i][j]);
        }
        __syncthreads();   // before next no overwrites sH / region A
    }

    // epilogue: + b2, store fp32
#pragma unroll
    for (int j = 0; j < 4; ++j) {
        const int col = wx * 64 + j * 16 + lm;
        const float b2v = b2[col];
#pragma unroll
        for (int i = 0; i < 4; ++i)
#pragma unroll
            for (int r = 0; r < 4; ++r) {
                const int row = wy * 64 + i * 16 + lq * 4 + r;
                op[(size_t)row * OW + col] = acc_o[i][j][r] + b2v;
            }
    }
}

extern "C" void kernel_launch(void* const* d_in, const int* in_sizes, int n_in,
                              void* d_out, int out_size, void* d_ws, size_t ws_size,
                              hipStream_t stream) {
    const float* share_x  = (const float*)d_in[0];
    const float* task_x0  = (const float*)d_in[1];
    const float* task_x1  = (const float*)d_in[2];
    const float* share_W1 = (const float*)d_in[3];
    const float* share_b1 = (const float*)d_in[4];
    const float* share_W2 = (const float*)d_in[5];
    const float* share_b2 = (const float*)d_in[6];
    const float* task_W1  = (const float*)d_in[7];
    const float* task_b1  = (const float*)d_in[8];
    const float* task_W2  = (const float*)d_in[9];
    const float* task_b2  = (const float*)d_in[10];
    float* out = (float*)d_out;

    unsigned short* w1t = (unsigned short*)d_ws;                 // 15*512*512 bf16
    unsigned short* w2t = w1t + (size_t)15 * H * H;              // 15*128*512 bf16

    prep_w1<<<dim3(128, 1, 15), 256, 0, stream>>>(share_W1, task_W1, w1t);
    prep_w2<<<dim3(32, 1, 15), 256, 0, stream>>>(share_W2, task_W2, w2t);
    expert_fused<<<dim3(128, 5, 3), 256, 0, stream>>>(
        share_x, task_x0, task_x1, share_b1, task_b1, share_b2, task_b2,
        w1t, w2t, out);
}